// Round 9
// baseline (328.299 us; speedup 1.0000x reference)
//
#include <hip/hip_runtime.h>
#include <hip/hip_bf16.h>

#define B_   2
#define T_   2048
#define DM_  2048
#define HQ_  32
#define HKV_ 8
#define HD_  64

typedef __attribute__((ext_vector_type(8))) short bf16x8;
typedef __attribute__((ext_vector_type(4))) float f32x4;
typedef __fp16 f16x4 __attribute__((ext_vector_type(4)));
typedef __fp16 f16x2 __attribute__((ext_vector_type(2)));

__device__ __forceinline__ unsigned short f2bf(float f) {
    unsigned int u = __float_as_uint(f);
    u = (u + 0x7fffu + ((u >> 16) & 1u)) >> 16;   // RNE
    return (unsigned short)u;
}

__device__ __forceinline__ void gload16(const unsigned short* g, unsigned short* l) {
    __builtin_amdgcn_global_load_lds(
        (const __attribute__((address_space(1))) unsigned int*)g,
        (__attribute__((address_space(3))) unsigned int*)l, 16, 0, 0);
}

// ---------------------------------------------------------------------------
// Workspace (ushort elements, 76 MiB total):
//   xb  : 8388608   (4096,2048)      bf16 x
//   Wb  : 6291456   (3072,2048)      bf16 [WQ;WK;WV]
//   WOb : 4194304   (2048,2048)      bf16 WO
//   Qb  : 8388608   (B,HQ,T,HD)      bf16 Q (RoPE'd + scaled in qkv epilogue)
//   Kb  : 2097152   (B,HKV,T,HD)     bf16 K (RoPE'd in qkv epilogue)
//   Vt  : 2097152   (B,HKV,HD,T)     f16 V transposed
//   Ob  : 8388608   (B,T,HQ*HD)      bf16 attention out
//                    (first 512 KB reused as the cos/sin table before attn)
// ---------------------------------------------------------------------------

#define CONV_N 4718592     // float4 convert work items

// -------- merged fp32 -> bf16 convert (x, WQ, WK, WV, WO) + trig table -----
__global__ __launch_bounds__(256) void convert_all(
    const float* __restrict__ x,  const float* __restrict__ WQ,
    const float* __restrict__ WK, const float* __restrict__ WV,
    const float* __restrict__ WO, unsigned short* __restrict__ ws,
    const int* __restrict__ pos,  float* __restrict__ trig)
{
    int i = blockIdx.x*256 + threadIdx.x;
    if (i >= CONV_N) {                    // trig table: T_*32 entries
        int j = i - CONV_N;
        if (j < T_*32) {
            int t = j >> 5, p = j & 31;
            float inv = exp2f(-0.4152410118609203f * (float)p); // theta^(-2p/64)
            float ang = (float)pos[t] * inv;
            float sn, cs;
            sincosf(ang, &sn, &cs);
            *(float2*)&trig[j*2] = make_float2(cs, sn);
        }
        return;
    }
    const float* src; unsigned short* dst; int rel;
    if (i < 2097152)      { src = x;  dst = ws;                 rel = i; }
    else if (i < 3145728) { src = WQ; dst = ws + 8388608;       rel = i - 2097152; }
    else if (i < 3407872) { src = WK; dst = ws + 8388608+4194304; rel = i - 3145728; }
    else if (i < 3670016) { src = WV; dst = ws + 8388608+5242880; rel = i - 3407872; }
    else                  { src = WO; dst = ws + 14680064;      rel = i - 3670016; }
    float4 v = *(const float4*)(src + (size_t)rel*4);
    uint2 pk;
    pk.x = (unsigned int)f2bf(v.x) | ((unsigned int)f2bf(v.y) << 16);
    pk.y = (unsigned int)f2bf(v.z) | ((unsigned int)f2bf(v.w) << 16);
    *(uint2*)(dst + (size_t)rel*4) = pk;
}

// ---------------- QKV projection: bf16 MFMA GEMM, tri-buffered -------------
// (R13/R15 structure: 128x128, counted vmcnt(4), depth-2 prefetch, period-3
// unroll, XCD swizzle, fused RoPE epilogue. Confirmed 83.5us.)
__global__ __launch_bounds__(256) void qkv_gemm_bf16(
    const unsigned short* __restrict__ Ab, const unsigned short* __restrict__ Wb,
    unsigned short* __restrict__ Qb, unsigned short* __restrict__ Kb,
    unsigned short* __restrict__ Vt, const float* __restrict__ trig)
{
    __shared__ unsigned short As[3][128*32];
    __shared__ unsigned short Bs[3][128*32];
    const int tid  = threadIdx.x;
    const int ln   = tid & 63;
    const int wv   = tid >> 6;
    const int wm   = (wv >> 1) * 64;
    const int wn   = (wv & 1) * 64;
    const int col  = ln & 15;
    const int quad = ln >> 4;

    // XCD-aware bijective block swizzle: 768 = 8 * 96
    const int bid = blockIdx.x;
    const int swz = (bid & 7) * 96 + (bid >> 3);
    const int n0  = (swz % 24) * 128;
    const int m0  = (swz / 24) * 128;

    // pre-swizzled global source column (involution: XOR by (row>>1)&3)
    const int cg = ((tid & 3) ^ ((tid >> 3) & 3)) * 8;
    const unsigned short* aG = Ab + (size_t)(m0 + (tid>>2))*DM_ + cg;
    const unsigned short* bG = Wb + (size_t)(n0 + (tid>>2))*DM_ + cg;
    const int ck = (quad ^ ((col >> 1) & 3)) * 8;   // swizzled read chunk

    f32x4 acc[4][4];
    #pragma unroll
    for (int i=0;i<4;++i)
        #pragma unroll
        for (int j=0;j<4;++j) { acc[i][j][0]=0.f; acc[i][j][1]=0.f; acc[i][j][2]=0.f; acc[i][j][3]=0.f; }

    auto stage = [&](int buf, int k0) {
        unsigned short* aL = &As[buf][wv*512];
        unsigned short* bL = &Bs[buf][wv*512];
        gload16(aG + k0,                  aL);
        gload16(aG + (size_t)64*DM_ + k0, aL + 2048);
        gload16(bG + k0,                  bL);
        gload16(bG + (size_t)64*DM_ + k0, bL + 2048);
    };

    auto kstep = [&](int bc, int k0v, int bstage, bool dostage, bool last) {
        if (last) asm volatile("s_waitcnt vmcnt(0)" ::: "memory");
        else      asm volatile("s_waitcnt vmcnt(4)" ::: "memory");
        __builtin_amdgcn_s_barrier();
        if (dostage) stage(bstage, k0v + 64);
        const unsigned short* Ac = As[bc];
        const unsigned short* Bc = Bs[bc];
        bf16x8 af[4], bfr[4];
        #pragma unroll
        for (int i2=0;i2<4;++i2) {
            af[i2]  = *(const bf16x8*)&Ac[(wm + i2*16 + col)*32 + ck];
            bfr[i2] = *(const bf16x8*)&Bc[(wn + i2*16 + col)*32 + ck];
        }
        #pragma unroll
        for (int i2=0;i2<4;++i2)
            #pragma unroll
            for (int j2=0;j2<4;++j2)
                acc[i2][j2] = __builtin_amdgcn_mfma_f32_16x16x32_bf16(af[i2], bfr[j2], acc[i2][j2], 0, 0, 0);
    };

    // prologue: tiles 0,1 in flight
    stage(0, 0);
    stage(1, 32);

    int k0 = 0;
    for (int rep = 0; rep < 20; ++rep) {       // kt = 0..59
        kstep(0, k0,      2, true, false);
        kstep(1, k0+32,   0, true, false);
        kstep(2, k0+64,   1, true, false);
        k0 += 96;
    }
    kstep(0, 1920, 2, true,  false);           // kt=60, stage tile 62
    kstep(1, 1952, 0, true,  false);           // kt=61, stage tile 63
    kstep(2, 1984, 1, false, false);           // kt=62
    kstep(0, 2016, 0, false, true);            // kt=63, tail drain

    // ---- epilogue: fused RoPE (Q scaled log2e/8, K unscaled), V transpose --
    const int b  = m0 >> 11;
    const int tb = m0 & 2047;
    #pragma unroll
    for (int j=0;j<4;++j) {
        const int n = n0 + wn + j*16 + col;
        if (n < 2560) {                         // Q or K: RoPE + pack
            const int d   = n & 63;
            const int p   = d >> 1;
            const bool ev = (d & 1) == 0;
            const float sc = (n < 2048) ? 0.18033688011112042f : 1.0f;  // log2e/8
            unsigned short* outp = (n < 2048)
                ? Qb + (((size_t)(b*HQ_  + (n>>6)))*T_)*HD_
                : Kb + (((size_t)(b*HKV_ + ((n-2048)>>6)))*T_)*HD_;
            #pragma unroll
            for (int i=0;i<4;++i) {
                const int t0 = tb + wm + i*16 + quad*4;
                #pragma unroll
                for (int r=0;r<4;++r) {
                    float self = acc[i][j][r];
                    float part = __shfl_xor(self, 1);
                    float2 cs  = *(const float2*)&trig[((t0 + r)*32 + p)*2];
                    float out  = ev ? (self*cs.x - part*cs.y)
                                    : (part*cs.y + self*cs.x);
                    out *= sc;
                    unsigned int pk = (unsigned int)f2bf(out);
                    unsigned int po = __shfl_xor(pk, 1);
                    if (ev)
                        *(unsigned int*)(outp + (size_t)(t0 + r)*HD_ + d) = pk | (po << 16);
                }
            }
        } else {                                // V: f16 transposed
            #pragma unroll
            for (int i=0;i<4;++i) {
                const int t = tb + wm + i*16 + quad*4;
                unsigned short* vp = Vt + (((size_t)(b*HKV_ + ((n-2560)>>6)))*HD_ + (n&63))*T_ + t;
                union { f16x2 h; unsigned int u; } c0, c1;
                c0.h = __builtin_amdgcn_cvt_pkrtz(acc[i][j][0], acc[i][j][1]);
                c1.h = __builtin_amdgcn_cvt_pkrtz(acc[i][j][2], acc[i][j][3]);
                *(unsigned int*)(vp)     = c0.u;
                *(unsigned int*)(vp + 2) = c1.u;
            }
        }
    }
}

// ---------------- MFMA flash attention, ADJACENT paired Q-tiles ------------
// R16: reverted to the R6 shared-fragment paired structure (the R8 state-
// split doubled LDS fragment reads — conflicts 6.4->8.65M — and idled 4/8
// waves half the time; 81.5->87.5us). Pairing changed from mirrored
// (bxi, 31-bxi) to ADJACENT (2g, 2g+1): per bh, wall iterations drop
// 392 -> 272 and B-only (half-efficiency) iterations drop 256 -> 16 —
// nearly every iteration now runs both states with shared K/V fragment
// loads. Block lengths become 2g+2 (2..32); longest blocks dispatch first
// (g = 15 - blockIdx.x) so greedy CU scheduling absorbs the variance.
// Kernel body is otherwise the verified R6/R13 code (light tile barriers).
__global__ __launch_bounds__(256, 2) void attn_mfma(
    const unsigned short* __restrict__ Qb, const unsigned short* __restrict__ Kb,
    const unsigned short* __restrict__ Vh, unsigned short* __restrict__ Ob)
{
    __shared__ unsigned short Ks[2][64*64];    // bf16 K rows (k), d chunks swizzled
    __shared__ unsigned short Vs[2][64*64];    // f16 V^T rows (d), k chunks swizzled

    const int tid  = threadIdx.x;
    const int lane = tid & 63;
    const int wave = tid >> 6;
    const int q16  = lane & 15;
    const int quad = lane >> 4;
    const int g    = 15 - blockIdx.x;     // longest blocks first
    const int bh   = blockIdx.y;
    const int b    = bh >> 5;
    const int h    = bh & 31;
    const int kvh  = h >> 2;
    const int qa   = 2*g;                 // 0,2,..,30
    const int qbt  = 2*g + 1;             // qa < qbt always; qbt >= 1
    const int qgA  = qa *64 + wave*16 + q16;
    const int qgB  = qbt*64 + wave*16 + q16;

    const unsigned short* kbase = Kb + ((size_t)(b*HKV_ + kvh))*T_*HD_;
    const unsigned short* vbase = Vh + ((size_t)(b*HKV_ + kvh))*(size_t)HD_*T_;

    const bf16x8 qA0 = *(const bf16x8*)(Qb + ((size_t)bh*T_ + qgA)*HD_ + quad*8);
    const bf16x8 qA1 = *(const bf16x8*)(Qb + ((size_t)bh*T_ + qgA)*HD_ + 32 + quad*8);
    const bf16x8 qB0 = *(const bf16x8*)(Qb + ((size_t)bh*T_ + qgB)*HD_ + quad*8);
    const bf16x8 qB1 = *(const bf16x8*)(Qb + ((size_t)bh*T_ + qgB)*HD_ + 32 + quad*8);

    f32x4 oA[4], oB[4];
    #pragma unroll
    for (int i=0;i<4;++i) {
        oA[i][0]=0.f; oA[i][1]=0.f; oA[i][2]=0.f; oA[i][3]=0.f;
        oB[i][0]=0.f; oB[i][1]=0.f; oB[i][2]=0.f; oB[i][3]=0.f;
    }
    float lA = 0.f, lB = 0.f;

    const int sr = tid >> 3;              // 0..31
    const int sj = tid & 7;               // 16B chunk
    const int sc = (sj ^ (sr & 7)) * 8;   // (sr+32)&7 == sr&7

    const int rk7 = q16 & 7;
    const int ck0 = (quad ^ rk7) * 8;
    const int ck1 = ((quad + 4) ^ rk7) * 8;

    auto smrow = [&](const f32x4 s, float& ps) -> f16x4 {
        float e0 = exp2f(s[0]), e1 = exp2f(s[1]);
        float e2 = exp2f(s[2]), e3 = exp2f(s[3]);
        ps += (e0+e1) + (e2+e3);
        union { f16x2 h[2]; f16x4 v; } c;
        c.h[0] = __builtin_amdgcn_cvt_pkrtz(e0, e1);
        c.h[1] = __builtin_amdgcn_cvt_pkrtz(e2, e3);
        return c.v;
    };

    // light barrier: ds ops visible, global prefetch stays in flight
    auto tile_barrier = [&]() {
        asm volatile("s_waitcnt lgkmcnt(0)" ::: "memory");
        __builtin_amdgcn_s_barrier();
        __builtin_amdgcn_sched_barrier(0);
    };

    uint4 kr0, kr1, vr0, vr1;
    kr0 = *(const uint4*)(kbase + (size_t)sr*HD_ + sj*8);
    kr1 = *(const uint4*)(kbase + (size_t)(sr+32)*HD_ + sj*8);
    vr0 = *(const uint4*)(vbase + (size_t)sr*T_ + sj*8);
    vr1 = *(const uint4*)(vbase + (size_t)(sr+32)*T_ + sj*8);
    *(uint4*)&Ks[0][sr*64 + sc]      = kr0;
    *(uint4*)&Ks[0][(sr+32)*64 + sc] = kr1;
    *(uint4*)&Vs[0][sr*64 + sc]      = vr0;
    *(uint4*)&Vs[0][(sr+32)*64 + sc] = vr1;
    // prefetch tile 1 (always exists: qbt >= 1)
    kr0 = *(const uint4*)(kbase + (size_t)(64+sr)*HD_ + sj*8);
    kr1 = *(const uint4*)(kbase + (size_t)(64+sr+32)*HD_ + sj*8);
    vr0 = *(const uint4*)(vbase + (size_t)sr*T_ + 64 + sj*8);
    vr1 = *(const uint4*)(vbase + (size_t)(sr+32)*T_ + 64 + sj*8);
    __syncthreads();

    int cur = 0;

    // ---- phase 1: both Q-states (kt <= qa < qbt), branchless body ----------
    for (int kt = 0; kt <= qa; ++kt) {
        const unsigned short* KsC = Ks[cur];
        const unsigned short* VsC = Vs[cur];
        const int nxt = cur ^ 1;

        f32x4 sB[4], sA[4];
        #pragma unroll
        for (int t=0;t<4;++t) {
            sB[t][0]=0.f; sB[t][1]=0.f; sB[t][2]=0.f; sB[t][3]=0.f;
            sA[t][0]=0.f; sA[t][1]=0.f; sA[t][2]=0.f; sA[t][3]=0.f;
        }
        f16x4 pfB[4];
        float psB = 0.f, psA = 0.f;

        __builtin_amdgcn_s_setprio(1);
        #pragma unroll
        for (int t = 0; t < 4; ++t) {
            const int rk = (t*16 + q16) * 64;
            bf16x8 a0 = *(const bf16x8*)&KsC[rk + ck0];
            bf16x8 a1 = *(const bf16x8*)&KsC[rk + ck1];
            sB[t] = __builtin_amdgcn_mfma_f32_16x16x32_bf16(a0, qB0, sB[t], 0, 0, 0);
            sB[t] = __builtin_amdgcn_mfma_f32_16x16x32_bf16(a1, qB1, sB[t], 0, 0, 0);
            sA[t] = __builtin_amdgcn_mfma_f32_16x16x32_bf16(a0, qA0, sA[t], 0, 0, 0);
            sA[t] = __builtin_amdgcn_mfma_f32_16x16x32_bf16(a1, qA1, sA[t], 0, 0, 0);
            if (t > 0) pfB[t-1] = smrow(sB[t-1], psB);
        }
        // stage tile kt+1 into buf^1 (always exists: kt+1 <= qa+1 = qbt)
        *(uint4*)&Ks[nxt][sr*64 + sc]      = kr0;
        *(uint4*)&Ks[nxt][(sr+32)*64 + sc] = kr1;
        *(uint4*)&Vs[nxt][sr*64 + sc]      = vr0;
        *(uint4*)&Vs[nxt][(sr+32)*64 + sc] = vr1;
        if (kt + 1 < qbt) {
            const int kn = (kt+2)*64;
            kr0 = *(const uint4*)(kbase + (size_t)(kn+sr)*HD_ + sj*8);
            kr1 = *(const uint4*)(kbase + (size_t)(kn+sr+32)*HD_ + sj*8);
            vr0 = *(const uint4*)(vbase + (size_t)sr*T_ + kn + sj*8);
            vr1 = *(const uint4*)(vbase + (size_t)(sr+32)*T_ + kn + sj*8);
        }
        pfB[3] = smrow(sB[3], psB);
        lB += psB;

        if (kt == qa) {   // causal boundary for state A (last phase-1 iter)
            #pragma unroll
            for (int t = 0; t < 4; ++t)
                #pragma unroll
                for (int r = 0; r < 4; ++r)
                    if (kt*64 + t*16 + quad*4 + r > qgA) sA[t][r] = -1e30f;
        }

        #pragma unroll
        for (int t = 0; t < 4; ++t) {
            const int cv = ((2*t + (quad>>1)) ^ rk7) * 8 + (quad&1)*4;
            f16x4 va[4];
            #pragma unroll
            for (int dt=0;dt<4;++dt)
                va[dt] = *(const f16x4*)&VsC[(dt*16 + q16)*64 + cv];
            #pragma unroll
            for (int dt=0;dt<4;++dt)
                oB[dt] = __builtin_amdgcn_mfma_f32_16x16x16f16(va[dt], pfB[t], oB[dt], 0, 0, 0);
            f16x4 pfA = smrow(sA[t], psA);
            #pragma unroll
            for (int dt=0;dt<4;++dt)
                oA[dt] = __builtin_amdgcn_mfma_f32_16x16x16f16(va[dt], pfA, oA[dt], 0, 0, 0);
        }
        lA += psA;
        __builtin_amdgcn_s_setprio(0);
        tile_barrier();
        cur ^= 1;
    }

    // ---- phase 2: state B only (qa < kt <= qbt; here exactly one iter) -----
    for (int kt = qa+1; kt <= qbt; ++kt) {
        const unsigned short* KsC = Ks[cur];
        const unsigned short* VsC = Vs[cur];
        const int nxt = cur ^ 1;

        f32x4 sB[4];
        #pragma unroll
        for (int t=0;t<4;++t) { sB[t][0]=0.f; sB[t][1]=0.f; sB[t][2]=0.f; sB[t][3]=0.f; }

        __builtin_amdgcn_s_setprio(1);
        #pragma unroll
        for (int t = 0; t < 4; ++t) {
            const int rk = (t*16 + q16) * 64;
            bf16x8 a0 = *(const bf16x8*)&KsC[rk + ck0];
            bf16x8 a1 = *(const bf16x8*)&KsC[rk + ck1];
            sB[t] = __builtin_amdgcn_mfma_f32_16x16x32_bf16(a0, qB0, sB[t], 0, 0, 0);
            sB[t] = __builtin_amdgcn_mfma_f32_16x16x32_bf16(a1, qB1, sB[t], 0, 0, 0);
        }
        if (kt < qbt) {
            *(uint4*)&Ks[nxt][sr*64 + sc]      = kr0;
            *(uint4*)&Ks[nxt][(sr+32)*64 + sc] = kr1;
            *(uint4*)&Vs[nxt][sr*64 + sc]      = vr0;
            *(uint4*)&Vs[nxt][(sr+32)*64 + sc] = vr1;
        }
        if (kt + 1 < qbt) {
            const int kn = (kt+2)*64;
            kr0 = *(const uint4*)(kbase + (size_t)(kn+sr)*HD_ + sj*8);
            kr1 = *(const uint4*)(kbase + (size_t)(kn+sr+32)*HD_ + sj*8);
            vr0 = *(const uint4*)(vbase + (size_t)sr*T_ + kn + sj*8);
            vr1 = *(const uint4*)(vbase + (size_t)(sr+32)*T_ + kn + sj*8);
        }
        if (kt == qbt) {  // causal boundary for state B (last iteration)
            #pragma unroll
            for (int t = 0; t < 4; ++t)
                #pragma unroll
                for (int r = 0; r < 4; ++r)
                    if (kt*64 + t*16 + quad*4 + r > qgB) sB[t][r] = -1e30f;
        }

        float psB = 0.f;
        #pragma unroll
        for (int t = 0; t < 4; ++t) {
            f16x4 pfB = smrow(sB[t], psB);
            const int cv = ((2*t + (quad>>1)) ^ rk7) * 8 + (quad&1)*4;
            #pragma unroll
            for (int dt=0;dt<4;++dt) {
                f16x4 va = *(const f16x4*)&VsC[(dt*16 + q16)*64 + cv];
                oB[dt] = __builtin_amdgcn_mfma_f32_16x16x16f16(va, pfB, oB[dt], 0, 0, 0);
            }
        }
        lB += psB;
        __builtin_amdgcn_s_setprio(0);
        tile_barrier();
        cur ^= 1;
    }

    lA += __shfl_xor(lA, 16); lA += __shfl_xor(lA, 32);
    lB += __shfl_xor(lB, 16); lB += __shfl_xor(lB, 32);
    const float rlA = 1.0f / lA;
    const float rlB = 1.0f / lB;
    unsigned short* opA = Ob + ((size_t)(b*T_ + qgA))*(HQ_*HD_) + h*HD_;
    unsigned short* opB = Ob + ((size_t)(b*T_ + qgB))*(HQ_*HD_) + h*HD_;
    #pragma unroll
    for (int dt = 0; dt < 4; ++dt) {
        uint2 pa, pb;
        pa.x = (unsigned int)f2bf(oA[dt][0]*rlA) | ((unsigned int)f2bf(oA[dt][1]*rlA) << 16);
        pa.y = (unsigned int)f2bf(oA[dt][2]*rlA) | ((unsigned int)f2bf(oA[dt][3]*rlA) << 16);
        pb.x = (unsigned int)f2bf(oB[dt][0]*rlB) | ((unsigned int)f2bf(oB[dt][1]*rlB) << 16);
        pb.y = (unsigned int)f2bf(oB[dt][2]*rlB) | ((unsigned int)f2bf(oB[dt][3]*rlB) << 16);
        *(uint2*)(opA + dt*16 + quad*4) = pa;
        *(uint2*)(opB + dt*16 + quad*4) = pb;
    }
}

// ---------------- Output projection: bf16 MFMA GEMM, tri-buffered, unrolled -
__global__ __launch_bounds__(256) void out_gemm_bf16(
    const unsigned short* __restrict__ Ab, const unsigned short* __restrict__ Wb,
    float* __restrict__ C)
{
    __shared__ unsigned short As[3][128*32];
    __shared__ unsigned short Bs[3][128*32];
    const int tid  = threadIdx.x;
    const int ln   = tid & 63;
    const int wv   = tid >> 6;
    const int wm   = (wv >> 1) * 64;
    const int wn   = (wv & 1) * 64;
    const int col  = ln & 15;
    const int quad = ln >> 4;

    // XCD-aware bijective block swizzle: 512 = 8 * 64
    const int bid = blockIdx.x;
    const int swz = (bid & 7) * 64 + (bid >> 3);
    const int n0  = (swz & 15) * 128;
    const int m0  = (swz >> 4) * 128;

    const int cg = ((tid & 3) ^ ((tid >> 3) & 3)) * 8;
    const unsigned short* aG = Ab + (size_t)(m0 + (tid>>2))*DM_ + cg;
    const unsigned short* bG = Wb + (size_t)(n0 + (tid>>2))*DM_ + cg;
    const int ck = (quad ^ ((col >> 1) & 3)) * 8;

    f32x4 acc[4][4];
    #pragma unroll
    for (int i=0;i<4;++i)
        #pragma unroll
        for (int j=0;j<4;++j) { acc[i][j][0]=0.f; acc[i][j][1]=0.f; acc[i][j][2]=0.f; acc[i][j][3]=0.f; }

    auto stage = [&](int buf, int k0) {
        unsigned short* aL = &As[buf][wv*512];
        unsigned short* bL = &Bs[buf][wv*512];
        gload16(aG + k0,                  aL);
        gload16(aG + (size_t)64*DM_ + k0, aL + 2048);
        gload16(bG + k0,                  bL);
        gload16(bG + (size_t)64*DM_ + k0, bL + 2048);
    };

    auto kstep = [&](int bc, int k0v, int bstage, bool dostage, bool last) {
        if (last) asm volatile("s_waitcnt vmcnt(0)" ::: "memory");
        else      asm volatile("s_waitcnt vmcnt(4)" ::: "memory");
        __builtin_amdgcn_s_barrier();
        if (dostage) stage(bstage, k0v + 64);
        const unsigned short* Ac = As[bc];
        const unsigned short* Bc = Bs[bc];
        bf16x8 af[4], bfr[4];
        #pragma unroll
        for (int i2=0;i2<4;++i2) {
            af[i2]  = *(const bf16x8*)&Ac[(wm + i2*16 + col)*32 + ck];
            bfr[i2] = *(const bf16x8*)&Bc[(wn + i2*16 + col)*32 + ck];
        }
        #pragma unroll
        for (int i2=0;i2<4;++i2)
            #pragma unroll
            for (int j2=0;j2<4;++j2)
                acc[i2][j2] = __builtin_amdgcn_mfma_f32_16x16x32_bf16(af[i2], bfr[j2], acc[i2][j2], 0, 0, 0);
    };

    stage(0, 0);
    stage(1, 32);

    int k0 = 0;
    for (int rep = 0; rep < 20; ++rep) {
        kstep(0, k0,      2, true, false);
        kstep(1, k0+32,   0, true, false);
        kstep(2, k0+64,   1, true, false);
        k0 += 96;
    }
    kstep(0, 1920, 2, true,  false);
    kstep(1, 1952, 0, true,  false);
    kstep(2, 1984, 1, false, false);
    kstep(0, 2016, 0, false, true);

    #pragma unroll
    for (int i=0;i<4;++i) {
        const int m = m0 + wm + i*16 + quad*4;
        #pragma unroll
        for (int j=0;j<4;++j) {
            const int n = n0 + wn + j*16 + col;
            #pragma unroll
            for (int r=0;r<4;++r)
                C[(size_t)(m + r)*DM_ + n] = acc[i][j][r];
        }
    }
}

extern "C" void kernel_launch(void* const* d_in, const int* in_sizes, int n_in,
                              void* d_out, int out_size, void* d_ws, size_t ws_size,
                              hipStream_t stream) {
    const float* x   = (const float*)d_in[0];
    const int*   pos = (const int*)  d_in[1];
    const float* WQ  = (const float*)d_in[2];
    const float* WK  = (const float*)d_in[3];
    const float* WV  = (const float*)d_in[4];
    const float* WO  = (const float*)d_in[5];
    float* out = (float*)d_out;

    unsigned short* xb  = (unsigned short*)d_ws;
    unsigned short* Wb  = xb  + (size_t)8388608;
    unsigned short* WOb = Wb  + (size_t)6291456;
    unsigned short* Qb  = WOb + (size_t)4194304;
    unsigned short* Kb  = Qb  + (size_t)8388608;
    unsigned short* Vt  = Kb  + (size_t)2097152;
    unsigned short* Ob  = Vt  + (size_t)2097152;
    float* trig = (float*)Ob;    // 512 KB scratch inside Ob (dead until attn)

    // 0) fp32 -> bf16 converts + trig table, single launch
    convert_all<<<18688, 256, 0, stream>>>(x, WQ, WK, WV, WO, (unsigned short*)d_ws, pos, trig);

    // 1) QKV projection + fused RoPE -> Qb/Kb bf16, Vt f16 transposed
    qkv_gemm_bf16<<<768, 256, 0, stream>>>(xb, Wb, Qb, Kb, Vt, trig);

    // 2) Causal GQA flash attention (adjacent paired Q-tiles, longest-first)
    dim3 g3(16, B_*HQ_);
    attn_mfma<<<g3, 256, 0, stream>>>(Qb, Kb, Vt, Ob);

    // 3) Output projection -> fp32 out (512 blocks, XCD-swizzled)
    out_gemm_bf16<<<512, 256, 0, stream>>>(Ob, WOb, out);
}

// Round 10
// 304.694 us; speedup vs baseline: 1.0775x; 1.0775x over previous
//
#include <hip/hip_runtime.h>
#include <hip/hip_bf16.h>

#define B_   2
#define T_   2048
#define DM_  2048
#define HQ_  32
#define HKV_ 8
#define HD_  64

typedef __attribute__((ext_vector_type(8))) short bf16x8;
typedef __attribute__((ext_vector_type(4))) float f32x4;
typedef __fp16 f16x4 __attribute__((ext_vector_type(4)));
typedef __fp16 f16x2 __attribute__((ext_vector_type(2)));

__device__ __forceinline__ unsigned short f2bf(float f) {
    unsigned int u = __float_as_uint(f);
    u = (u + 0x7fffu + ((u >> 16) & 1u)) >> 16;   // RNE
    return (unsigned short)u;
}

__device__ __forceinline__ void gload16(const unsigned short* g, unsigned short* l) {
    __builtin_amdgcn_global_load_lds(
        (const __attribute__((address_space(1))) unsigned int*)g,
        (__attribute__((address_space(3))) unsigned int*)l, 16, 0, 0);
}

// ---------------------------------------------------------------------------
// Workspace (ushort elements, 76 MiB total):
//   xb  : 8388608   (4096,2048)      bf16 x
//   Wb  : 6291456   (3072,2048)      bf16 [WQ;WK;WV]
//   WOb : 4194304   (2048,2048)      bf16 WO
//   Qb  : 8388608   (B,HQ,T,HD)      bf16 Q (RoPE'd + scaled in qkv epilogue)
//   Kb  : 2097152   (B,HKV,T,HD)     bf16 K (RoPE'd in qkv epilogue)
//   Vt  : 2097152   (B,HKV,HD,T)     f16 V transposed
//   Ob  : 8388608   (B,T,HQ*HD)      bf16 attention out
//                    (first 512 KB reused as the cos/sin table before attn)
// ---------------------------------------------------------------------------

#define CONV_N 4718592     // float4 convert work items

// -------- merged fp32 -> bf16 convert (x, WQ, WK, WV, WO) + trig table -----
__global__ __launch_bounds__(256) void convert_all(
    const float* __restrict__ x,  const float* __restrict__ WQ,
    const float* __restrict__ WK, const float* __restrict__ WV,
    const float* __restrict__ WO, unsigned short* __restrict__ ws,
    const int* __restrict__ pos,  float* __restrict__ trig)
{
    int i = blockIdx.x*256 + threadIdx.x;
    if (i >= CONV_N) {                    // trig table: T_*32 entries
        int j = i - CONV_N;
        if (j < T_*32) {
            int t = j >> 5, p = j & 31;
            float inv = exp2f(-0.4152410118609203f * (float)p); // theta^(-2p/64)
            float ang = (float)pos[t] * inv;
            float sn, cs;
            sincosf(ang, &sn, &cs);
            *(float2*)&trig[j*2] = make_float2(cs, sn);
        }
        return;
    }
    const float* src; unsigned short* dst; int rel;
    if (i < 2097152)      { src = x;  dst = ws;                 rel = i; }
    else if (i < 3145728) { src = WQ; dst = ws + 8388608;       rel = i - 2097152; }
    else if (i < 3407872) { src = WK; dst = ws + 8388608+4194304; rel = i - 3145728; }
    else if (i < 3670016) { src = WV; dst = ws + 8388608+5242880; rel = i - 3407872; }
    else                  { src = WO; dst = ws + 14680064;      rel = i - 3670016; }
    float4 v = *(const float4*)(src + (size_t)rel*4);
    uint2 pk;
    pk.x = (unsigned int)f2bf(v.x) | ((unsigned int)f2bf(v.y) << 16);
    pk.y = (unsigned int)f2bf(v.z) | ((unsigned int)f2bf(v.w) << 16);
    *(uint2*)(dst + (size_t)rel*4) = pk;
}

// ---------------- QKV projection: bf16 MFMA GEMM, tri-buffered -------------
// (R13/R15 structure, confirmed 82-85us)
__global__ __launch_bounds__(256) void qkv_gemm_bf16(
    const unsigned short* __restrict__ Ab, const unsigned short* __restrict__ Wb,
    unsigned short* __restrict__ Qb, unsigned short* __restrict__ Kb,
    unsigned short* __restrict__ Vt, const float* __restrict__ trig)
{
    __shared__ unsigned short As[3][128*32];
    __shared__ unsigned short Bs[3][128*32];
    const int tid  = threadIdx.x;
    const int ln   = tid & 63;
    const int wv   = tid >> 6;
    const int wm   = (wv >> 1) * 64;
    const int wn   = (wv & 1) * 64;
    const int col  = ln & 15;
    const int quad = ln >> 4;

    // XCD-aware bijective block swizzle: 768 = 8 * 96
    const int bid = blockIdx.x;
    const int swz = (bid & 7) * 96 + (bid >> 3);
    const int n0  = (swz % 24) * 128;
    const int m0  = (swz / 24) * 128;

    // pre-swizzled global source column (involution: XOR by (row>>1)&3)
    const int cg = ((tid & 3) ^ ((tid >> 3) & 3)) * 8;
    const unsigned short* aG = Ab + (size_t)(m0 + (tid>>2))*DM_ + cg;
    const unsigned short* bG = Wb + (size_t)(n0 + (tid>>2))*DM_ + cg;
    const int ck = (quad ^ ((col >> 1) & 3)) * 8;   // swizzled read chunk

    f32x4 acc[4][4];
    #pragma unroll
    for (int i=0;i<4;++i)
        #pragma unroll
        for (int j=0;j<4;++j) { acc[i][j][0]=0.f; acc[i][j][1]=0.f; acc[i][j][2]=0.f; acc[i][j][3]=0.f; }

    auto stage = [&](int buf, int k0) {
        unsigned short* aL = &As[buf][wv*512];
        unsigned short* bL = &Bs[buf][wv*512];
        gload16(aG + k0,                  aL);
        gload16(aG + (size_t)64*DM_ + k0, aL + 2048);
        gload16(bG + k0,                  bL);
        gload16(bG + (size_t)64*DM_ + k0, bL + 2048);
    };

    auto kstep = [&](int bc, int k0v, int bstage, bool dostage, bool last) {
        if (last) asm volatile("s_waitcnt vmcnt(0)" ::: "memory");
        else      asm volatile("s_waitcnt vmcnt(4)" ::: "memory");
        __builtin_amdgcn_s_barrier();
        if (dostage) stage(bstage, k0v + 64);
        const unsigned short* Ac = As[bc];
        const unsigned short* Bc = Bs[bc];
        bf16x8 af[4], bfr[4];
        #pragma unroll
        for (int i2=0;i2<4;++i2) {
            af[i2]  = *(const bf16x8*)&Ac[(wm + i2*16 + col)*32 + ck];
            bfr[i2] = *(const bf16x8*)&Bc[(wn + i2*16 + col)*32 + ck];
        }
        #pragma unroll
        for (int i2=0;i2<4;++i2)
            #pragma unroll
            for (int j2=0;j2<4;++j2)
                acc[i2][j2] = __builtin_amdgcn_mfma_f32_16x16x32_bf16(af[i2], bfr[j2], acc[i2][j2], 0, 0, 0);
    };

    // prologue: tiles 0,1 in flight
    stage(0, 0);
    stage(1, 32);

    int k0 = 0;
    for (int rep = 0; rep < 20; ++rep) {       // kt = 0..59
        kstep(0, k0,      2, true, false);
        kstep(1, k0+32,   0, true, false);
        kstep(2, k0+64,   1, true, false);
        k0 += 96;
    }
    kstep(0, 1920, 2, true,  false);           // kt=60, stage tile 62
    kstep(1, 1952, 0, true,  false);           // kt=61, stage tile 63
    kstep(2, 1984, 1, false, false);           // kt=62
    kstep(0, 2016, 0, false, true);            // kt=63, tail drain

    // ---- epilogue: fused RoPE (Q scaled log2e/8, K unscaled), V transpose --
    const int b  = m0 >> 11;
    const int tb = m0 & 2047;
    #pragma unroll
    for (int j=0;j<4;++j) {
        const int n = n0 + wn + j*16 + col;
        if (n < 2560) {                         // Q or K: RoPE + pack
            const int d   = n & 63;
            const int p   = d >> 1;
            const bool ev = (d & 1) == 0;
            const float sc = (n < 2048) ? 0.18033688011112042f : 1.0f;  // log2e/8
            unsigned short* outp = (n < 2048)
                ? Qb + (((size_t)(b*HQ_  + (n>>6)))*T_)*HD_
                : Kb + (((size_t)(b*HKV_ + ((n-2048)>>6)))*T_)*HD_;
            #pragma unroll
            for (int i=0;i<4;++i) {
                const int t0 = tb + wm + i*16 + quad*4;
                #pragma unroll
                for (int r=0;r<4;++r) {
                    float self = acc[i][j][r];
                    float part = __shfl_xor(self, 1);
                    float2 cs  = *(const float2*)&trig[((t0 + r)*32 + p)*2];
                    float out  = ev ? (self*cs.x - part*cs.y)
                                    : (part*cs.y + self*cs.x);
                    out *= sc;
                    unsigned int pk = (unsigned int)f2bf(out);
                    unsigned int po = __shfl_xor(pk, 1);
                    if (ev)
                        *(unsigned int*)(outp + (size_t)(t0 + r)*HD_ + d) = pk | (po << 16);
                }
            }
        } else {                                // V: f16 transposed
            #pragma unroll
            for (int i=0;i<4;++i) {
                const int t = tb + wm + i*16 + quad*4;
                unsigned short* vp = Vt + (((size_t)(b*HKV_ + ((n-2560)>>6)))*HD_ + (n&63))*T_ + t;
                union { f16x2 h; unsigned int u; } c0, c1;
                c0.h = __builtin_amdgcn_cvt_pkrtz(acc[i][j][0], acc[i][j][1]);
                c1.h = __builtin_amdgcn_cvt_pkrtz(acc[i][j][2], acc[i][j][3]);
                *(unsigned int*)(vp)     = c0.u;
                *(unsigned int*)(vp + 2) = c1.u;
            }
        }
    }
}

// ---------------- MFMA flash attention: 4-state strided blocks -------------
// R17: adjacent pairing (R16) regressed (108us, occupancy 13.7%) — variable
// block lengths (2..32 iters) wrecked scheduling; total state-iterations are
// invariant so only SHARED per-iteration cost is saveable. This version keeps
// the shared-fragment structure but amortizes shared cost 4 ways with
// BALANCED geometry: block g owns q-tiles {g, g+8, g+16, g+24} (g=0..7).
//  * wall length = g+25 -> 25..32 iters (±12% balance)
//  * grid (8,64) = 512 blocks = exactly 2/CU (32KB LDS x2) — no quantization
//  * per-bh wall iters 228 vs 392 (mirrored); up to 96 MFMA per barrier
//  * 4 descending phases (4/3/2/1 active states), each state masked at its
//    own last active iteration; phase bodies macro-generated so all state
//    indexing is compile-time (no scratch).
__device__ __forceinline__ f16x4 smrow_fn(const f32x4 s, float& ps) {
    float e0 = exp2f(s[0]), e1 = exp2f(s[1]);
    float e2 = exp2f(s[2]), e3 = exp2f(s[3]);
    ps += (e0+e1) + (e2+e3);
    union { f16x2 hh[2]; f16x4 v; } c;
    c.hh[0] = __builtin_amdgcn_cvt_pkrtz(e0, e1);
    c.hh[1] = __builtin_amdgcn_cvt_pkrtz(e2, e3);
    return c.v;
}

__global__ __launch_bounds__(256, 2) void attn_mfma(
    const unsigned short* __restrict__ Qb, const unsigned short* __restrict__ Kb,
    const unsigned short* __restrict__ Vh, unsigned short* __restrict__ Ob)
{
    __shared__ unsigned short Ks[2][64*64];    // bf16 K rows (k), d chunks swizzled
    __shared__ unsigned short Vs[2][64*64];    // f16 V^T rows (d), k chunks swizzled

    const int tid  = threadIdx.x;
    const int lane = tid & 63;
    const int wave = tid >> 6;
    const int q16  = lane & 15;
    const int quad = lane >> 4;
    const int g    = 7 - blockIdx.x;      // longest blocks dispatch first
    const int bh   = blockIdx.y;
    const int b    = bh >> 5;
    const int h    = bh & 31;
    const int kvh  = h >> 2;
    const int q3t  = g + 24;              // last kv-tile overall (24..31)

    const unsigned short* kbase = Kb + ((size_t)(b*HKV_ + kvh))*T_*HD_;
    const unsigned short* vbase = Vh + ((size_t)(b*HKV_ + kvh))*(size_t)HD_*T_;

    int qg[4];
    bf16x8 qf0[4], qf1[4];
    #pragma unroll
    for (int s=0;s<4;++s) {
        qg[s]  = (g + 8*s)*64 + wave*16 + q16;
        qf0[s] = *(const bf16x8*)(Qb + ((size_t)bh*T_ + qg[s])*HD_ + quad*8);
        qf1[s] = *(const bf16x8*)(Qb + ((size_t)bh*T_ + qg[s])*HD_ + 32 + quad*8);
    }

    f32x4 o[4][4];                        // [state][dt]
    float l[4];
    #pragma unroll
    for (int s=0;s<4;++s) {
        l[s] = 0.f;
        #pragma unroll
        for (int dt=0;dt<4;++dt) { o[s][dt][0]=0.f; o[s][dt][1]=0.f; o[s][dt][2]=0.f; o[s][dt][3]=0.f; }
    }

    const int sr = tid >> 3;              // 0..31
    const int sj = tid & 7;               // 16B chunk
    const int sc = (sj ^ (sr & 7)) * 8;   // (sr+32)&7 == sr&7

    const int rk7 = q16 & 7;
    const int ck0 = (quad ^ rk7) * 8;
    const int ck1 = ((quad + 4) ^ rk7) * 8;

    // light barrier: ds ops visible, global prefetch stays in flight
    auto tile_barrier = [&]() {
        asm volatile("s_waitcnt lgkmcnt(0)" ::: "memory");
        __builtin_amdgcn_s_barrier();
        __builtin_amdgcn_sched_barrier(0);
    };

    uint4 kr0, kr1, vr0, vr1;
    kr0 = *(const uint4*)(kbase + (size_t)sr*HD_ + sj*8);
    kr1 = *(const uint4*)(kbase + (size_t)(sr+32)*HD_ + sj*8);
    vr0 = *(const uint4*)(vbase + (size_t)sr*T_ + sj*8);
    vr1 = *(const uint4*)(vbase + (size_t)(sr+32)*T_ + sj*8);
    *(uint4*)&Ks[0][sr*64 + sc]      = kr0;
    *(uint4*)&Ks[0][(sr+32)*64 + sc] = kr1;
    *(uint4*)&Vs[0][sr*64 + sc]      = vr0;
    *(uint4*)&Vs[0][(sr+32)*64 + sc] = vr1;
    // prefetch tile 1 (always exists: q3t >= 24)
    kr0 = *(const uint4*)(kbase + (size_t)(64+sr)*HD_ + sj*8);
    kr1 = *(const uint4*)(kbase + (size_t)(64+sr+32)*HD_ + sj*8);
    vr0 = *(const uint4*)(vbase + (size_t)sr*T_ + 64 + sj*8);
    vr1 = *(const uint4*)(vbase + (size_t)(sr+32)*T_ + 64 + sj*8);
    __syncthreads();

    int cur = 0;
    int kt  = 0;

// One kv-tile iteration with NS active states (states 4-NS..3). The state
// expiring this phase (s0 = 4-NS) is masked at its boundary kt == qg-tile.
#define TILE_BODY(NS, QEND)                                                    \
  {                                                                            \
    const unsigned short* KsC = Ks[cur];                                       \
    const unsigned short* VsC = Vs[cur];                                       \
    const int nxt = cur ^ 1;                                                   \
    f32x4 sS[4][4];                                                            \
    _Pragma("unroll")                                                          \
    for (int s=4-(NS);s<4;++s)                                                 \
      _Pragma("unroll")                                                        \
      for (int t=0;t<4;++t) { sS[s][t][0]=0.f; sS[s][t][1]=0.f;                \
                              sS[s][t][2]=0.f; sS[s][t][3]=0.f; }              \
    __builtin_amdgcn_s_setprio(1);                                             \
    _Pragma("unroll")                                                          \
    for (int t=0;t<4;++t) {                                                    \
      const int rk = (t*16 + q16) * 64;                                        \
      bf16x8 a0 = *(const bf16x8*)&KsC[rk + ck0];                              \
      bf16x8 a1 = *(const bf16x8*)&KsC[rk + ck1];                              \
      _Pragma("unroll")                                                        \
      for (int s=4-(NS);s<4;++s) {                                             \
        sS[s][t] = __builtin_amdgcn_mfma_f32_16x16x32_bf16(a0, qf0[s], sS[s][t], 0, 0, 0); \
        sS[s][t] = __builtin_amdgcn_mfma_f32_16x16x32_bf16(a1, qf1[s], sS[s][t], 0, 0, 0); \
      }                                                                        \
    }                                                                          \
    if (kt < q3t) {                                                            \
      *(uint4*)&Ks[nxt][sr*64 + sc]      = kr0;                                \
      *(uint4*)&Ks[nxt][(sr+32)*64 + sc] = kr1;                                \
      *(uint4*)&Vs[nxt][sr*64 + sc]      = vr0;                                \
      *(uint4*)&Vs[nxt][(sr+32)*64 + sc] = vr1;                                \
    }                                                                          \
    if (kt + 1 < q3t) {                                                        \
      const int kn = (kt+2)*64;                                                \
      kr0 = *(const uint4*)(kbase + (size_t)(kn+sr)*HD_ + sj*8);               \
      kr1 = *(const uint4*)(kbase + (size_t)(kn+sr+32)*HD_ + sj*8);            \
      vr0 = *(const uint4*)(vbase + (size_t)sr*T_ + kn + sj*8);                \
      vr1 = *(const uint4*)(vbase + (size_t)(sr+32)*T_ + kn + sj*8);           \
    }                                                                          \
    if (kt == (QEND)) {                     /* mask expiring state */          \
      const int s0 = 4-(NS);                                                   \
      _Pragma("unroll")                                                        \
      for (int t=0;t<4;++t)                                                    \
        _Pragma("unroll")                                                      \
        for (int r=0;r<4;++r)                                                  \
          if (kt*64 + t*16 + quad*4 + r > qg[s0]) sS[s0][t][r] = -1e30f;       \
    }                                                                          \
    f16x4 pf[4][4];                                                            \
    _Pragma("unroll")                                                          \
    for (int s=4-(NS);s<4;++s) {                                               \
      float ps = 0.f;                                                          \
      _Pragma("unroll")                                                        \
      for (int t=0;t<4;++t) pf[s][t] = smrow_fn(sS[s][t], ps);                 \
      l[s] += ps;                                                              \
    }                                                                          \
    _Pragma("unroll")                                                          \
    for (int t=0;t<4;++t) {                                                    \
      const int cv = ((2*t + (quad>>1)) ^ rk7) * 8 + (quad&1)*4;               \
      f16x4 va[4];                                                             \
      _Pragma("unroll")                                                        \
      for (int dt=0;dt<4;++dt)                                                 \
        va[dt] = *(const f16x4*)&VsC[(dt*16 + q16)*64 + cv];                   \
      _Pragma("unroll")                                                        \
      for (int s=4-(NS);s<4;++s)                                               \
        _Pragma("unroll")                                                      \
        for (int dt=0;dt<4;++dt)                                               \
          o[s][dt] = __builtin_amdgcn_mfma_f32_16x16x16f16(va[dt], pf[s][t], o[s][dt], 0, 0, 0); \
    }                                                                          \
    __builtin_amdgcn_s_setprio(0);                                             \
    tile_barrier();                                                            \
    cur ^= 1;                                                                  \
  }

    for (; kt <= g;      ++kt) TILE_BODY(4, g)        // states 0-3; s0 expires
    for (; kt <= g + 8;  ++kt) TILE_BODY(3, g + 8)    // states 1-3
    for (; kt <= g + 16; ++kt) TILE_BODY(2, g + 16)   // states 2-3
    for (; kt <= g + 24; ++kt) TILE_BODY(1, g + 24)   // state 3

#undef TILE_BODY

    #pragma unroll
    for (int s=0;s<4;++s) {
        float ls = l[s];
        ls += __shfl_xor(ls, 16); ls += __shfl_xor(ls, 32);
        const float rl = 1.0f / ls;
        unsigned short* op = Ob + ((size_t)(b*T_ + qg[s]))*(HQ_*HD_) + h*HD_;
        #pragma unroll
        for (int dt = 0; dt < 4; ++dt) {
            uint2 pk;
            pk.x = (unsigned int)f2bf(o[s][dt][0]*rl) | ((unsigned int)f2bf(o[s][dt][1]*rl) << 16);
            pk.y = (unsigned int)f2bf(o[s][dt][2]*rl) | ((unsigned int)f2bf(o[s][dt][3]*rl) << 16);
            *(uint2*)(op + dt*16 + quad*4) = pk;
        }
    }
}

// ---------------- Output projection: bf16 MFMA GEMM, tri-buffered, unrolled -
__global__ __launch_bounds__(256) void out_gemm_bf16(
    const unsigned short* __restrict__ Ab, const unsigned short* __restrict__ Wb,
    float* __restrict__ C)
{
    __shared__ unsigned short As[3][128*32];
    __shared__ unsigned short Bs[3][128*32];
    const int tid  = threadIdx.x;
    const int ln   = tid & 63;
    const int wv   = tid >> 6;
    const int wm   = (wv >> 1) * 64;
    const int wn   = (wv & 1) * 64;
    const int col  = ln & 15;
    const int quad = ln >> 4;

    // XCD-aware bijective block swizzle: 512 = 8 * 64
    const int bid = blockIdx.x;
    const int swz = (bid & 7) * 64 + (bid >> 3);
    const int n0  = (swz & 15) * 128;
    const int m0  = (swz >> 4) * 128;

    const int cg = ((tid & 3) ^ ((tid >> 3) & 3)) * 8;
    const unsigned short* aG = Ab + (size_t)(m0 + (tid>>2))*DM_ + cg;
    const unsigned short* bG = Wb + (size_t)(n0 + (tid>>2))*DM_ + cg;
    const int ck = (quad ^ ((col >> 1) & 3)) * 8;

    f32x4 acc[4][4];
    #pragma unroll
    for (int i=0;i<4;++i)
        #pragma unroll
        for (int j=0;j<4;++j) { acc[i][j][0]=0.f; acc[i][j][1]=0.f; acc[i][j][2]=0.f; acc[i][j][3]=0.f; }

    auto stage = [&](int buf, int k0) {
        unsigned short* aL = &As[buf][wv*512];
        unsigned short* bL = &Bs[buf][wv*512];
        gload16(aG + k0,                  aL);
        gload16(aG + (size_t)64*DM_ + k0, aL + 2048);
        gload16(bG + k0,                  bL);
        gload16(bG + (size_t)64*DM_ + k0, bL + 2048);
    };

    auto kstep = [&](int bc, int k0v, int bstage, bool dostage, bool last) {
        if (last) asm volatile("s_waitcnt vmcnt(0)" ::: "memory");
        else      asm volatile("s_waitcnt vmcnt(4)" ::: "memory");
        __builtin_amdgcn_s_barrier();
        if (dostage) stage(bstage, k0v + 64);
        const unsigned short* Ac = As[bc];
        const unsigned short* Bc = Bs[bc];
        bf16x8 af[4], bfr[4];
        #pragma unroll
        for (int i2=0;i2<4;++i2) {
            af[i2]  = *(const bf16x8*)&Ac[(wm + i2*16 + col)*32 + ck];
            bfr[i2] = *(const bf16x8*)&Bc[(wn + i2*16 + col)*32 + ck];
        }
        #pragma unroll
        for (int i2=0;i2<4;++i2)
            #pragma unroll
            for (int j2=0;j2<4;++j2)
                acc[i2][j2] = __builtin_amdgcn_mfma_f32_16x16x32_bf16(af[i2], bfr[j2], acc[i2][j2], 0, 0, 0);
    };

    stage(0, 0);
    stage(1, 32);

    int k0 = 0;
    for (int rep = 0; rep < 20; ++rep) {
        kstep(0, k0,      2, true, false);
        kstep(1, k0+32,   0, true, false);
        kstep(2, k0+64,   1, true, false);
        k0 += 96;
    }
    kstep(0, 1920, 2, true,  false);
    kstep(1, 1952, 0, true,  false);
    kstep(2, 1984, 1, false, false);
    kstep(0, 2016, 0, false, true);

    #pragma unroll
    for (int i=0;i<4;++i) {
        const int m = m0 + wm + i*16 + quad*4;
        #pragma unroll
        for (int j=0;j<4;++j) {
            const int n = n0 + wn + j*16 + col;
            #pragma unroll
            for (int r=0;r<4;++r)
                C[(size_t)(m + r)*DM_ + n] = acc[i][j][r];
        }
    }
}

extern "C" void kernel_launch(void* const* d_in, const int* in_sizes, int n_in,
                              void* d_out, int out_size, void* d_ws, size_t ws_size,
                              hipStream_t stream) {
    const float* x   = (const float*)d_in[0];
    const int*   pos = (const int*)  d_in[1];
    const float* WQ  = (const float*)d_in[2];
    const float* WK  = (const float*)d_in[3];
    const float* WV  = (const float*)d_in[4];
    const float* WO  = (const float*)d_in[5];
    float* out = (float*)d_out;

    unsigned short* xb  = (unsigned short*)d_ws;
    unsigned short* Wb  = xb  + (size_t)8388608;
    unsigned short* WOb = Wb  + (size_t)6291456;
    unsigned short* Qb  = WOb + (size_t)4194304;
    unsigned short* Kb  = Qb  + (size_t)8388608;
    unsigned short* Vt  = Kb  + (size_t)2097152;
    unsigned short* Ob  = Vt  + (size_t)2097152;
    float* trig = (float*)Ob;    // 512 KB scratch inside Ob (dead until attn)

    // 0) fp32 -> bf16 converts + trig table, single launch
    convert_all<<<18688, 256, 0, stream>>>(x, WQ, WK, WV, WO, (unsigned short*)d_ws, pos, trig);

    // 1) QKV projection + fused RoPE -> Qb/Kb bf16, Vt f16 transposed
    qkv_gemm_bf16<<<768, 256, 0, stream>>>(xb, Wb, Qb, Kb, Vt, trig);

    // 2) Causal GQA flash attention (4-state strided blocks, 2/CU exact)
    dim3 g3(8, B_*HQ_);
    attn_mfma<<<g3, 256, 0, stream>>>(Qb, Kb, Vt, Ob);

    // 3) Output projection -> fp32 out (512 blocks, XCD-swizzled)
    out_gemm_bf16<<<512, 256, 0, stream>>>(Ob, WOb, out);
}